// Round 13
// baseline (547.214 us; speedup 1.0000x reference)
//
#include <hip/hip_runtime.h>
#include <hip/hip_bf16.h>
#include <stdint.h>
#include <math.h>

#define T_SEQ 2048
#define CDIM  2048
#define NB    4
#define NH    16
#define NKV   4
#define HD    128

typedef __attribute__((ext_vector_type(8))) short short8;
typedef __attribute__((ext_vector_type(4))) float f32x4;

__device__ __forceinline__ void gload_lds16(const void* g, void* l) {
  __builtin_amdgcn_global_load_lds((const __attribute__((address_space(1))) void*)g,
                                   (__attribute__((address_space(3))) void*)l, 16, 0, 0);
}

__device__ __forceinline__ f32x4 mfma_bf16(short8 a, short8 b, f32x4 c) {
  return __builtin_amdgcn_mfma_f32_16x16x32_bf16(a, b, c, 0, 0, 0);
}

__device__ __forceinline__ unsigned short f2bf(float x) {
  union { float f; unsigned u; } v; v.f = x;
  unsigned r = v.u + 0x7fffu + ((v.u >> 16) & 1u);
  return (unsigned short)(r >> 16);
}

// pack 2 f32 -> 2 bf16 in one u32 (lo = a, hi = b), RTNE
__device__ __forceinline__ unsigned pk_bf16(float a, float b) {
  unsigned r;
  asm("v_cvt_pk_bf16_f32 %0, %1, %2" : "=v"(r) : "v"(a), "v"(b));
  return r;
}

// 2^x via HW transcendental
__device__ __forceinline__ float exp2_fast(float x) {
  float r;
  asm("v_exp_f32 %0, %1" : "=v"(r) : "v"(x));
  return r;
}

// s_barrier + code-motion fence (s_barrier alone is IntrNoMem in LLVM)
__device__ __forceinline__ void barrier_hard() {
  __builtin_amdgcn_s_barrier();
  __builtin_amdgcn_sched_barrier(0);
}

// ---------------- fp32 -> bf16 convert, all 5 tensors in one launch ----------------
__global__ void cvt_all(const float* __restrict__ x,  const float* __restrict__ qw,
                        const float* __restrict__ kw, const float* __restrict__ vw,
                        const float* __restrict__ ow,
                        unsigned short* __restrict__ xb,  unsigned short* __restrict__ qwb,
                        unsigned short* __restrict__ kwb, unsigned short* __restrict__ vwb,
                        unsigned short* __restrict__ owb) {
  const int bid = blockIdx.x;
  const float* src; unsigned short* dst; int base, nb, n4;
  if (bid < 2048)      { src = x;  dst = xb;  base = 0;    nb = 2048; n4 = 4194304; }
  else if (bid < 2560) { src = qw; dst = qwb; base = 2048; nb = 512;  n4 = 1048576; }
  else if (bid < 2688) { src = kw; dst = kwb; base = 2560; nb = 128;  n4 = 262144;  }
  else if (bid < 2816) { src = vw; dst = vwb; base = 2688; nb = 128;  n4 = 262144;  }
  else                 { src = ow; dst = owb; base = 2816; nb = 512;  n4 = 1048576; }
  const int stride = nb * 256;
  for (int i = (bid - base) * 256 + threadIdx.x; i < n4; i += stride) {
    float4 v = *(const float4*)(src + (size_t)i * 4);
    ushort4 o;
    o.x = f2bf(v.x); o.y = f2bf(v.y); o.z = f2bf(v.z); o.w = f2bf(v.w);
    *(ushort4*)(dst + (size_t)i * 4) = o;
  }
}

// ======== 256-tile 8-phase GEMM (modes 0 and 1): C[M,N] = A @ W^T ========
// MODE 0: fp32 out [M,N].  MODE 1: Q — RoPE + gain*(1/sqrt(d))*log2e, bf16 (B,NH,T,HD).
template<int MODE>
__launch_bounds__(512, 2)
__global__ void gemm256(const unsigned short* __restrict__ A,
                        const unsigned short* __restrict__ W,
                        int N, int K,
                        unsigned short* __restrict__ obf,
                        float* __restrict__ of32,
                        const float* __restrict__ gain)
{
  __shared__ alignas(16) short As[2][2][256 * 32];   // [dbuf][kk][row][32k]  64 KB
  __shared__ alignas(16) short Bs[2][2][256 * 32];   // 64 KB
  const int tid = threadIdx.x;
  const int lane = tid & 63, w = tid >> 6;
  const int wr = w >> 2, wc = w & 3;                 // 2M x 4N wave grid
  const int lr = lane & 15, lg = lane >> 4;

  const int nwg  = gridDim.x * gridDim.y;            // 256, %8==0
  const int orig = blockIdx.y * gridDim.x + blockIdx.x;
  const int cpx  = nwg >> 3;
  const int swz  = (orig & 7) * cpx + (orig >> 3);
  const int m0 = (swz / gridDim.x) * 256, n0 = (swz % gridDim.x) * 256;

  f32x4 acc[8][4] = {};
  const int nkt = K >> 6;
  const int rsw = (lr >> 1) & 3;                     // read-side chunk swizzle

  auto stageA = [&](int kt, int buf, int kk) {
#pragma unroll
    for (int i = 0; i < 2; ++i) {
      int t = i * 512 + tid;
      int row = t >> 2;
      int cs = (t & 3) ^ ((t >> 3) & 3);             // source pre-swizzle
      gload_lds16(A + (size_t)(m0 + row) * K + kt * 64 + kk * 32 + cs * 8,
                  (char*)&As[buf][kk][0] + i * 8192 + w * 1024);
    }
  };
  auto stageB = [&](int kt, int buf, int kk) {
#pragma unroll
    for (int i = 0; i < 2; ++i) {
      int t = i * 512 + tid;
      int row = t >> 2;
      int cs = (t & 3) ^ ((t >> 3) & 3);
      gload_lds16(W + (size_t)(n0 + row) * K + kt * 64 + kk * 32 + cs * 8,
                  (char*)&Bs[buf][kk][0] + i * 8192 + w * 1024);
    }
  };

  // prologue: tile 0 fully staged; retire k0 halves, keep k1 in flight
  stageA(0, 0, 0); stageB(0, 0, 0); stageA(0, 0, 1); stageB(0, 0, 1);
  asm volatile("s_waitcnt vmcnt(4)" ::: "memory");
  __builtin_amdgcn_s_barrier();

  int cur = 0;
  for (int kt = 0; kt < nkt; ++kt) {
    const int tn = (kt + 1 < nkt) ? kt + 1 : kt;     // clamp keeps ledger uniform
#pragma unroll
    for (int kk = 0; kk < 2; ++kk) {
      // -- even phase: B-frags (reused) + A-frags fm0-3; stage A-half(tn,kk)
      short8 bfr[4], af[4];
#pragma unroll
      for (int fn = 0; fn < 4; ++fn) {
        int rb = wc * 64 + fn * 16 + lr;
        bfr[fn] = *(const short8*)((const char*)&Bs[cur][kk][0] + rb * 64 + ((lg ^ rsw) << 4));
      }
#pragma unroll
      for (int fm = 0; fm < 4; ++fm) {
        int ra = wr * 128 + fm * 16 + lr;
        af[fm] = *(const short8*)((const char*)&As[cur][kk][0] + ra * 64 + ((lg ^ rsw) << 4));
      }
      stageA(tn, cur ^ 1, kk);
      __builtin_amdgcn_s_barrier();
      __builtin_amdgcn_s_setprio(1);
#pragma unroll
      for (int fm = 0; fm < 4; ++fm)
#pragma unroll
        for (int fn = 0; fn < 4; ++fn)
          acc[fm][fn] = mfma_bf16(af[fm], bfr[fn], acc[fm][fn]);
      __builtin_amdgcn_s_setprio(0);
      __builtin_amdgcn_s_barrier();

      // -- odd phase: A-frags fm4-7; stage B-half(tn,kk); counted vmcnt
#pragma unroll
      for (int fm = 0; fm < 4; ++fm) {
        int ra = wr * 128 + (4 + fm) * 16 + lr;
        af[fm] = *(const short8*)((const char*)&As[cur][kk][0] + ra * 64 + ((lg ^ rsw) << 4));
      }
      stageB(tn, cur ^ 1, kk);
      asm volatile("s_waitcnt vmcnt(4)" ::: "memory");  // retires halves needed 2 phases on
      __builtin_amdgcn_s_barrier();
      __builtin_amdgcn_s_setprio(1);
#pragma unroll
      for (int fm = 0; fm < 4; ++fm)
#pragma unroll
        for (int fn = 0; fn < 4; ++fn)
          acc[4 + fm][fn] = mfma_bf16(af[fm], bfr[fn], acc[4 + fm][fn]);
      __builtin_amdgcn_s_setprio(0);
      __builtin_amdgcn_s_barrier();
    }
    cur ^= 1;
  }
  asm volatile("s_waitcnt vmcnt(0)" ::: "memory");   // drain DMA before exit

  // epilogue: D lane map = [row=lg*4+r][col=lr] per 16x16 fragment
#pragma unroll
  for (int fm = 0; fm < 8; ++fm) {
    const int mbase = m0 + wr * 128 + fm * 16 + lg * 4;
#pragma unroll
    for (int fn = 0; fn < 4; ++fn) {
      const int ncol = n0 + wc * 64 + fn * 16 + lr;
      if constexpr (MODE == 0) {
#pragma unroll
        for (int r = 0; r < 4; ++r)
          of32[(size_t)(mbase + r) * N + ncol] = acc[fm][fn][r];
      } else {
        const int hh = ncol >> 7;
        const int d  = ncol & 127;
        const bool rope = ((wc & 1) == 0) && (fn == 0);   // d<16, wave-uniform
#pragma unroll
        for (int r = 0; r < 4; ++r) {
          float val = acc[fm][fn][r];
          const int m  = mbase + r;
          const int t  = m & (T_SEQ - 1);
          const int bb = m >> 11;
          if (rope) {
            float partner = __shfl_xor(val, 8);           // partner d^8
            float invf = exp2f(-(float)(d & 7) * 1.6609640474436813f);
            float ang = (float)t * invf;
            float sn, cn;
            sincosf(ang, &sn, &cn);
            float rot = (d < 8) ? -partner : partner;
            val = val * cn + rot * sn;
          }
          val *= gain[hh] * 0.12751742676f;               // fold 1/sqrt(128)*log2e
          obf[(size_t)((bb * NH + hh) * T_SEQ + t) * HD + d] = f2bf(val);
        }
      }
    }
  }
}

// ---------------- fused K+V projection (128-tile) ----------------
// W = [k_w; v_w], N=1024. Block n-tile = exactly one head (block-uniform hh).
// hh<4: K head — RoPE(d<16), bf16 (B,NKV,T,HD).
// hh>=4: V head — V^T written DIRECTLY (via padded LDS re-tile) to Vt (B,NKV,HD,T);
//        fp32 second output = kv-head 0 broadcast to all NKV slots.
__launch_bounds__(256, 2)
__global__ void gemm_kv(const unsigned short* __restrict__ A,
                        const unsigned short* __restrict__ W,
                        unsigned short* __restrict__ Kout,
                        unsigned short* __restrict__ Vt,
                        float* __restrict__ vout)
{
  __shared__ alignas(16) short As[128 * 64];
  __shared__ alignas(16) short Bs[128 * 64];
  __shared__ alignas(16) short Ts[128 * 132];   // [d][t] pad-132 transpose tile
  const int K = CDIM;
  const int tid = threadIdx.x;
  const int lane = tid & 63, w = tid >> 6;
  const int wr = w >> 1, wc = w & 1;
  const int lr = lane & 15, lg = lane >> 4;

  const int nwg  = gridDim.x * gridDim.y;       // 512, %8==0
  const int orig = blockIdx.y * gridDim.x + blockIdx.x;
  const int cpx  = nwg >> 3;
  const int swz  = (orig & 7) * cpx + (orig >> 3);
  const int m0 = (swz / gridDim.x) * 128, n0 = (swz % gridDim.x) * 128;

  f32x4 acc[4][4] = {};

  const int nkt = K >> 6;
  for (int kt = 0; kt < nkt; ++kt) {
    __syncthreads();
#pragma unroll
    for (int q = 0; q < 4; ++q) {
      int s = (w * 4 + q) * 64 + lane;
      int row = s >> 3;
      int cs2 = (s & 7) ^ (row & 7);
      gload_lds16(A + (size_t)(m0 + row) * K + (kt << 6) + cs2 * 8,
                  (char*)As + (w * 4 + q) * 1024);
      gload_lds16(W + (size_t)(n0 + row) * K + (kt << 6) + cs2 * 8,
                  (char*)Bs + (w * 4 + q) * 1024);
    }
    __syncthreads();
#pragma unroll
    for (int ks = 0; ks < 2; ++ks) {
      short8 af[4], bfr[4];
#pragma unroll
      for (int i = 0; i < 4; ++i) {
        int ra = wr * 64 + i * 16 + lr;
        int rb = wc * 64 + i * 16 + lr;
        af[i]  = *(const short8*)(As + ra * 64 + (((ks * 4 + lg) ^ (ra & 7)) << 3));
        bfr[i] = *(const short8*)(Bs + rb * 64 + (((ks * 4 + lg) ^ (rb & 7)) << 3));
      }
#pragma unroll
      for (int i = 0; i < 4; ++i)
#pragma unroll
        for (int j = 0; j < 4; ++j)
          acc[i][j] = mfma_bf16(af[i], bfr[j], acc[i][j]);
    }
  }

  const int hh = n0 >> 7;           // block-uniform head index
  const int bb = m0 >> 11;          // block-uniform batch
  const int tb = m0 & (T_SEQ - 1);  // block-uniform t base

  if (hh < 4) {
    // ---- K head: RoPE on d<16, linear bf16 write ----
#pragma unroll
    for (int i = 0; i < 4; ++i) {
      const int tl = wr * 64 + i * 16 + lg * 4;
#pragma unroll
      for (int j = 0; j < 4; ++j) {
        const int d = wc * 64 + j * 16 + lr;
        const bool rope = (wc == 0) && (j == 0);   // d<16, wave-uniform
#pragma unroll
        for (int r = 0; r < 4; ++r) {
          float val = acc[i][j][r];
          const int t = tb + tl + r;
          if (rope) {
            float partner = __shfl_xor(val, 8);
            float invf = exp2f(-(float)(d & 7) * 1.6609640474436813f);
            float ang = (float)t * invf;
            float sn, cn;
            sincosf(ang, &sn, &cn);
            float rot = (d < 8) ? -partner : partner;
            val = val * cn + rot * sn;
          }
          Kout[(size_t)((bb * NKV + hh) * T_SEQ + t) * HD + d] = f2bf(val);
        }
      }
    }
  } else {
    // ---- V head: vout broadcast (head 0) + transpose via LDS -> Vt ----
    const int hv = hh - 4;
#pragma unroll
    for (int i = 0; i < 4; ++i) {
      const int tl = wr * 64 + i * 16 + lg * 4;
#pragma unroll
      for (int j = 0; j < 4; ++j) {
        const int d = wc * 64 + j * 16 + lr;
        if (hv == 0) {
#pragma unroll
          for (int r = 0; r < 4; ++r) {
            float val = acc[i][j][r];
#pragma unroll
            for (int rep = 0; rep < NKV; ++rep)
              vout[(size_t)((bb * NKV + rep) * T_SEQ + tb + tl + r) * HD + d] = val;
          }
        }
        uint2 w2;
        w2.x = pk_bf16(acc[i][j][0], acc[i][j][1]);
        w2.y = pk_bf16(acc[i][j][2], acc[i][j][3]);
        *(uint2*)(Ts + d * 132 + tl) = w2;
      }
    }
    __syncthreads();
    // coalesced V^T writeout: thread pair covers one d row (128 t)
    const int d = tid >> 1, off = (tid & 1) * 64;
    unsigned short* dst = Vt + ((size_t)(bb * NKV + hv) * HD + d) * T_SEQ + tb + off;
    const short* srcp = Ts + d * 132 + off;
#pragma unroll
    for (int jj = 0; jj < 8; ++jj)
      *(short8*)(dst + jj * 8) = *(const short8*)(srcp + jj * 8);
  }
}

// ---------------- flash attention, causal, GQA ----------------
// Dual-head reuse + TLP: KVBLK=32, 4 waves / 256 thr, 40 KB LDS -> 4 blocks/CU
// = 16 waves/CU (4/SIMD). Grid 32 qtiles (zig-ordered for balance) x 8 head-
// pairs x 4 batch = 1024 blocks = exact capacity. Fixed-baseline softmax
// P = 2^(S-16) in MFMA C-init. Counted-vmcnt K/V-split pipeline (2-load
// stages; vmcnt 4/2, never drains in-loop). Barriers hardened.
__launch_bounds__(256, 4)
__global__ void attn_fwd(const unsigned short* __restrict__ Q,
                         const unsigned short* __restrict__ Kg,
                         const unsigned short* __restrict__ Vt,
                         unsigned short* __restrict__ O)
{
  __shared__ alignas(16) short Ks[2][32 * 128];   // 16 KB
  __shared__ alignas(16) short Vs[2][128 * 32];   // 16 KB
  __shared__ alignas(16) short Ps[128 * 32];      //  8 KB (head0 rows 0-63, head1 +64)

  const int bx = blockIdx.x;                      // 0..31
  const int qtile = (bx & 1) ? (31 - (bx >> 1)) : (bx >> 1);   // zig: balances any window
  const int hp = blockIdx.y, b = blockIdx.z;      // head pair 0..7
  const int kvh = hp >> 1;
  const int h0 = kvh * 4 + (hp & 1) * 2, h1 = h0 + 1;
  const int tid = threadIdx.x, lane = tid & 63, w = tid >> 6;   // w 0..3
  const int lr = lane & 15, lg = lane >> 4;

  const unsigned short* Qb0 = Q  + ((size_t)(b * NH  + h0)  * T_SEQ) * HD;
  const unsigned short* Qb1 = Q  + ((size_t)(b * NH  + h1)  * T_SEQ) * HD;
  const unsigned short* Kb  = Kg + ((size_t)(b * NKV + kvh) * T_SEQ) * HD;
  const unsigned short* Vtb = Vt + ((size_t)(b * NKV + kvh) * HD) * T_SEQ;

  auto stageK = [&](int kt, int buf) {
#pragma unroll
    for (int i = 0; i < 2; ++i) {   // 32 rows x 16 chunks = 512, 2 per thread
      int s = i * 256 + tid;
      int row = s >> 4, c = s & 15, cs = c ^ (row & 7);
      gload_lds16(Kb + (size_t)(kt * 32 + row) * HD + cs * 8,
                  (char*)&Ks[buf][0] + i * 4096 + w * 1024);
    }
  };
  auto stageV = [&](int kt, int buf) {
#pragma unroll
    for (int i = 0; i < 2; ++i) {   // 128 rows x 4 chunks = 512
      int s = i * 256 + tid;
      int row = s >> 2, c = s & 3, cs = c ^ (row & 3);
      gload_lds16(Vtb + (size_t)row * T_SEQ + kt * 32 + cs * 8,
                  (char*)&Vs[buf][0] + i * 4096 + w * 1024);
    }
  };

  const int rw = qtile * 64 + w * 16;   // wave's first q row
  const int qg = rw + lr;               // lane's q row (same for both heads)

  short8 qf0[4], qf1[4];
#pragma unroll
  for (int ks = 0; ks < 4; ++ks) {
    qf0[ks] = *(const short8*)(Qb0 + (size_t)qg * HD + ks * 32 + lg * 8);
    qf1[ks] = *(const short8*)(Qb1 + (size_t)qg * HD + ks * 32 + lg * 8);
  }

  f32x4 acc0[8] = {}, acc1[8] = {};
  float lrow0 = 0.0f, lrow1 = 0.0f;

  const int nkt = 2 * qtile + 2;        // KVBLK=32 tiles covering keys <= qtile*64+63

  stageK(0, 0);
  stageV(0, 0);
  asm volatile("s_waitcnt vmcnt(2)" ::: "memory");   // K(0) landed, V(0) in flight
  barrier_hard();
  int cur = 0;

  const f32x4 minit = {-16.f, -16.f, -16.f, -16.f};  // fixed softmax baseline

  for (int kt = 0; kt < nkt; ++kt) {
    const int tn = (kt + 1 < nkt) ? kt + 1 : kt;
    stageK(tn, cur ^ 1);                // out: V(t)2 + K(t+1)2 = 4

    {
      const short* KL = &Ks[cur][0];
      f32x4 s0[2] = {minit, minit};
      f32x4 s1[2] = {minit, minit};
      __builtin_amdgcn_s_setprio(1);
#pragma unroll
      for (int kb = 0; kb < 2; ++kb) {
        int key = kb * 16 + lr;
#pragma unroll
        for (int ks = 0; ks < 4; ++ks) {
          short8 kf = *(const short8*)(KL + key * 128 + (((ks * 4 + lg) ^ (key & 7)) << 3));
          s0[kb] = mfma_bf16(kf, qf0[ks], s0[kb]);
          s1[kb] = mfma_bf16(kf, qf1[ks], s1[kb]);
        }
      }
      __builtin_amdgcn_s_setprio(0);

      if (kt * 32 + 31 > rw) {          // wave-uniform; mask both heads identically
#pragma unroll
        for (int kb = 0; kb < 2; ++kb)
#pragma unroll
          for (int r = 0; r < 4; ++r)
            if (kt * 32 + kb * 16 + lg * 4 + r > qg) {
              s0[kb][r] = -3.0e38f;
              s1[kb][r] = -3.0e38f;
            }
      }

      // P = 2^(S-16); in-lane sums; pack to LDS (b64 writes)
      float sum0 = 0.f, sum1 = 0.f;
#pragma unroll
      for (int kb = 0; kb < 2; ++kb) {
        int cc = (kb * 2 + (lg >> 1)) ^ (lr & 3);
        {
          float p0 = exp2_fast(s0[kb][0]);
          float p1 = exp2_fast(s0[kb][1]);
          float p2 = exp2_fast(s0[kb][2]);
          float p3 = exp2_fast(s0[kb][3]);
          sum0 += (p0 + p1) + (p2 + p3);
          uint2 w2;
          w2.x = pk_bf16(p0, p1);
          w2.y = pk_bf16(p2, p3);
          *(uint2*)(Ps + (w * 16 + lr) * 32 + (cc << 3) + ((lg & 1) << 2)) = w2;
        }
        {
          float p0 = exp2_fast(s1[kb][0]);
          float p1 = exp2_fast(s1[kb][1]);
          float p2 = exp2_fast(s1[kb][2]);
          float p3 = exp2_fast(s1[kb][3]);
          sum1 += (p0 + p1) + (p2 + p3);
          uint2 w2;
          w2.x = pk_bf16(p0, p1);
          w2.y = pk_bf16(p2, p3);
          *(uint2*)(Ps + (64 + w * 16 + lr) * 32 + (cc << 3) + ((lg & 1) << 2)) = w2;
        }
      }
      lrow0 += sum0;
      lrow1 += sum1;
    }

    stageV(tn, cur ^ 1);                // out: 6
    asm volatile("s_waitcnt vmcnt(4)" ::: "memory");  // V(t) landed
    barrier_hard();

    {
      const short* VL = &Vs[cur][0];
      const int r0 = w * 16 + lr, r1 = 64 + w * 16 + lr;
      short8 pf0 = *(const short8*)(Ps + r0 * 32 + ((lg ^ (lr & 3)) << 3));
      short8 pf1 = *(const short8*)(Ps + r1 * 32 + ((lg ^ (lr & 3)) << 3));
      __builtin_amdgcn_s_setprio(1);
#pragma unroll
      for (int db = 0; db < 8; ++db) {
        int vrow = db * 16 + lr;
        short8 vf = *(const short8*)(VL + vrow * 32 + ((lg ^ (vrow & 3)) << 3));
        acc0[db] = mfma_bf16(vf, pf0, acc0[db]);
        acc1[db] = mfma_bf16(vf, pf1, acc1[db]);
      }
      __builtin_amdgcn_s_setprio(0);
    }

    asm volatile("s_waitcnt vmcnt(2)" ::: "memory");  // K(t+1) landed
    barrier_hard();
    cur ^= 1;
  }

  asm volatile("s_waitcnt vmcnt(0)" ::: "memory");
  barrier_hard();

  // epilogue: cross-lane lrow reduce, normalize + store both heads
  lrow0 += __shfl_xor(lrow0, 16); lrow0 += __shfl_xor(lrow0, 32);
  lrow1 += __shfl_xor(lrow1, 16); lrow1 += __shfl_xor(lrow1, 32);
  float inv0 = 1.0f / lrow0, inv1 = 1.0f / lrow1;
#pragma unroll
  for (int db = 0; db < 8; ++db) {
    uint2 o2;
    o2.x = pk_bf16(acc0[db][0] * inv0, acc0[db][1] * inv0);
    o2.y = pk_bf16(acc0[db][2] * inv0, acc0[db][3] * inv0);
    *(uint2*)(O + (size_t)(b * T_SEQ + qg) * CDIM + h0 * HD + db * 16 + lg * 4) = o2;
    uint2 o3;
    o3.x = pk_bf16(acc1[db][0] * inv1, acc1[db][1] * inv1);
    o3.y = pk_bf16(acc1[db][2] * inv1, acc1[db][3] * inv1);
    *(uint2*)(O + (size_t)(b * T_SEQ + qg) * CDIM + h1 * HD + db * 16 + lg * 4) = o3;
  }
}

// ---------------- launch ----------------
extern "C" void kernel_launch(void* const* d_in, const int* in_sizes, int n_in,
                              void* d_out, int out_size, void* d_ws, size_t ws_size,
                              hipStream_t stream) {
  (void)in_sizes; (void)n_in; (void)out_size; (void)ws_size;
  const float* x    = (const float*)d_in[0];
  const float* qw   = (const float*)d_in[1];
  const float* kw   = (const float*)d_in[2];
  const float* vw   = (const float*)d_in[3];
  const float* ow   = (const float*)d_in[4];
  const float* gain = (const float*)d_in[5];
  float* out  = (float*)d_out;
  float* vout = out + (size_t)NB * T_SEQ * CDIM;

  char* ws = (char*)d_ws;
  unsigned short* xb  = (unsigned short*)(ws);              // 33554432 B (also Ab)
  unsigned short* Qb  = (unsigned short*)(ws + 33554432);   // 33554432
  unsigned short* Kb  = (unsigned short*)(ws + 67108864);   //  8388608
  unsigned short* qwb = (unsigned short*)(ws + 83886080);   //  8388608 (later: Vt)
  unsigned short* kwb = (unsigned short*)(ws + 92274688);   //  2097152 (+vwb contiguous)
  unsigned short* vwb = (unsigned short*)(ws + 94371840);   //  2097152
  unsigned short* owb = (unsigned short*)(ws + 96468992);   //  8388608  -> 104857600 total
  unsigned short* Ab  = xb;
  unsigned short* Vtb = qwb;   // [B*NKV][HD][T] bf16; qwb dead after gemm256<1>

  cvt_all<<<3328, 256, 0, stream>>>(x, qw, kw, vw, ow, xb, qwb, kwb, vwb, owb);

  gemm256<1><<<dim3(8, 32), 512, 0, stream>>>(xb, qwb, CDIM, CDIM, Qb, nullptr, gain);
  gemm_kv<<<dim3(8, 64), 256, 0, stream>>>(xb, kwb, Kb, Vtb, vout);

  attn_fwd<<<dim3(32, 8, 4), 256, 0, stream>>>(Qb, Kb, Vtb, Ab);

  gemm256<0><<<dim3(8, 32), 512, 0, stream>>>(Ab, owb, CDIM, CDIM, nullptr, out, nullptr);
}

// Round 14
// 293.224 us; speedup vs baseline: 1.8662x; 1.8662x over previous
//
#include <hip/hip_runtime.h>
#include <hip/hip_bf16.h>
#include <stdint.h>
#include <math.h>

#define T_SEQ 2048
#define CDIM  2048
#define NB    4
#define NH    16
#define NKV   4
#define HD    128

typedef __attribute__((ext_vector_type(8))) short short8;
typedef __attribute__((ext_vector_type(4))) float f32x4;

__device__ __forceinline__ void gload_lds16(const void* g, void* l) {
  __builtin_amdgcn_global_load_lds((const __attribute__((address_space(1))) void*)g,
                                   (__attribute__((address_space(3))) void*)l, 16, 0, 0);
}

__device__ __forceinline__ f32x4 mfma_bf16(short8 a, short8 b, f32x4 c) {
  return __builtin_amdgcn_mfma_f32_16x16x32_bf16(a, b, c, 0, 0, 0);
}

__device__ __forceinline__ unsigned short f2bf(float x) {
  union { float f; unsigned u; } v; v.f = x;
  unsigned r = v.u + 0x7fffu + ((v.u >> 16) & 1u);
  return (unsigned short)(r >> 16);
}

// pack 2 f32 -> 2 bf16 in one u32 (lo = a, hi = b), RTNE
__device__ __forceinline__ unsigned pk_bf16(float a, float b) {
  unsigned r;
  asm("v_cvt_pk_bf16_f32 %0, %1, %2" : "=v"(r) : "v"(a), "v"(b));
  return r;
}

// 2^x via HW transcendental
__device__ __forceinline__ float exp2_fast(float x) {
  float r;
  asm("v_exp_f32 %0, %1" : "=v"(r) : "v"(x));
  return r;
}

// s_barrier + code-motion fence (s_barrier alone is IntrNoMem in LLVM)
__device__ __forceinline__ void barrier_hard() {
  __builtin_amdgcn_s_barrier();
  __builtin_amdgcn_sched_barrier(0);
}

// ---------------- fp32 -> bf16 convert, all 5 tensors in one launch ----------------
__global__ void cvt_all(const float* __restrict__ x,  const float* __restrict__ qw,
                        const float* __restrict__ kw, const float* __restrict__ vw,
                        const float* __restrict__ ow,
                        unsigned short* __restrict__ xb,  unsigned short* __restrict__ qwb,
                        unsigned short* __restrict__ kwb, unsigned short* __restrict__ vwb,
                        unsigned short* __restrict__ owb) {
  const int bid = blockIdx.x;
  const float* src; unsigned short* dst; int base, nb, n4;
  if (bid < 2048)      { src = x;  dst = xb;  base = 0;    nb = 2048; n4 = 4194304; }
  else if (bid < 2560) { src = qw; dst = qwb; base = 2048; nb = 512;  n4 = 1048576; }
  else if (bid < 2688) { src = kw; dst = kwb; base = 2560; nb = 128;  n4 = 262144;  }
  else if (bid < 2816) { src = vw; dst = vwb; base = 2688; nb = 128;  n4 = 262144;  }
  else                 { src = ow; dst = owb; base = 2816; nb = 512;  n4 = 1048576; }
  const int stride = nb * 256;
  for (int i = (bid - base) * 256 + threadIdx.x; i < n4; i += stride) {
    float4 v = *(const float4*)(src + (size_t)i * 4);
    ushort4 o;
    o.x = f2bf(v.x); o.y = f2bf(v.y); o.z = f2bf(v.z); o.w = f2bf(v.w);
    *(ushort4*)(dst + (size_t)i * 4) = o;
  }
}

// ======== 256-tile 8-phase GEMM (modes 0 and 1): C[M,N] = A @ W^T ========
// MODE 0: fp32 out [M,N].  MODE 1: Q — RoPE + gain*(1/sqrt(d))*log2e, bf16 (B,NH,T,HD).
template<int MODE>
__launch_bounds__(512, 2)
__global__ void gemm256(const unsigned short* __restrict__ A,
                        const unsigned short* __restrict__ W,
                        int N, int K,
                        unsigned short* __restrict__ obf,
                        float* __restrict__ of32,
                        const float* __restrict__ gain)
{
  __shared__ alignas(16) short As[2][2][256 * 32];   // [dbuf][kk][row][32k]  64 KB
  __shared__ alignas(16) short Bs[2][2][256 * 32];   // 64 KB
  const int tid = threadIdx.x;
  const int lane = tid & 63, w = tid >> 6;
  const int wr = w >> 2, wc = w & 3;                 // 2M x 4N wave grid
  const int lr = lane & 15, lg = lane >> 4;

  const int nwg  = gridDim.x * gridDim.y;            // 256, %8==0
  const int orig = blockIdx.y * gridDim.x + blockIdx.x;
  const int cpx  = nwg >> 3;
  const int swz  = (orig & 7) * cpx + (orig >> 3);
  const int m0 = (swz / gridDim.x) * 256, n0 = (swz % gridDim.x) * 256;

  f32x4 acc[8][4] = {};
  const int nkt = K >> 6;
  const int rsw = (lr >> 1) & 3;                     // read-side chunk swizzle

  auto stageA = [&](int kt, int buf, int kk) {
#pragma unroll
    for (int i = 0; i < 2; ++i) {
      int t = i * 512 + tid;
      int row = t >> 2;
      int cs = (t & 3) ^ ((t >> 3) & 3);             // source pre-swizzle
      gload_lds16(A + (size_t)(m0 + row) * K + kt * 64 + kk * 32 + cs * 8,
                  (char*)&As[buf][kk][0] + i * 8192 + w * 1024);
    }
  };
  auto stageB = [&](int kt, int buf, int kk) {
#pragma unroll
    for (int i = 0; i < 2; ++i) {
      int t = i * 512 + tid;
      int row = t >> 2;
      int cs = (t & 3) ^ ((t >> 3) & 3);
      gload_lds16(W + (size_t)(n0 + row) * K + kt * 64 + kk * 32 + cs * 8,
                  (char*)&Bs[buf][kk][0] + i * 8192 + w * 1024);
    }
  };

  // prologue: tile 0 fully staged; retire k0 halves, keep k1 in flight
  stageA(0, 0, 0); stageB(0, 0, 0); stageA(0, 0, 1); stageB(0, 0, 1);
  asm volatile("s_waitcnt vmcnt(4)" ::: "memory");
  __builtin_amdgcn_s_barrier();

  int cur = 0;
  for (int kt = 0; kt < nkt; ++kt) {
    const int tn = (kt + 1 < nkt) ? kt + 1 : kt;     // clamp keeps ledger uniform
#pragma unroll
    for (int kk = 0; kk < 2; ++kk) {
      // -- even phase: B-frags (reused) + A-frags fm0-3; stage A-half(tn,kk)
      short8 bfr[4], af[4];
#pragma unroll
      for (int fn = 0; fn < 4; ++fn) {
        int rb = wc * 64 + fn * 16 + lr;
        bfr[fn] = *(const short8*)((const char*)&Bs[cur][kk][0] + rb * 64 + ((lg ^ rsw) << 4));
      }
#pragma unroll
      for (int fm = 0; fm < 4; ++fm) {
        int ra = wr * 128 + fm * 16 + lr;
        af[fm] = *(const short8*)((const char*)&As[cur][kk][0] + ra * 64 + ((lg ^ rsw) << 4));
      }
      stageA(tn, cur ^ 1, kk);
      __builtin_amdgcn_s_barrier();
      __builtin_amdgcn_s_setprio(1);
#pragma unroll
      for (int fm = 0; fm < 4; ++fm)
#pragma unroll
        for (int fn = 0; fn < 4; ++fn)
          acc[fm][fn] = mfma_bf16(af[fm], bfr[fn], acc[fm][fn]);
      __builtin_amdgcn_s_setprio(0);
      __builtin_amdgcn_s_barrier();

      // -- odd phase: A-frags fm4-7; stage B-half(tn,kk); counted vmcnt
#pragma unroll
      for (int fm = 0; fm < 4; ++fm) {
        int ra = wr * 128 + (4 + fm) * 16 + lr;
        af[fm] = *(const short8*)((const char*)&As[cur][kk][0] + ra * 64 + ((lg ^ rsw) << 4));
      }
      stageB(tn, cur ^ 1, kk);
      asm volatile("s_waitcnt vmcnt(4)" ::: "memory");  // retires halves needed 2 phases on
      __builtin_amdgcn_s_barrier();
      __builtin_amdgcn_s_setprio(1);
#pragma unroll
      for (int fm = 0; fm < 4; ++fm)
#pragma unroll
        for (int fn = 0; fn < 4; ++fn)
          acc[4 + fm][fn] = mfma_bf16(af[fm], bfr[fn], acc[4 + fm][fn]);
      __builtin_amdgcn_s_setprio(0);
      __builtin_amdgcn_s_barrier();
    }
    cur ^= 1;
  }
  asm volatile("s_waitcnt vmcnt(0)" ::: "memory");   // drain DMA before exit

  // epilogue: D lane map = [row=lg*4+r][col=lr] per 16x16 fragment
#pragma unroll
  for (int fm = 0; fm < 8; ++fm) {
    const int mbase = m0 + wr * 128 + fm * 16 + lg * 4;
#pragma unroll
    for (int fn = 0; fn < 4; ++fn) {
      const int ncol = n0 + wc * 64 + fn * 16 + lr;
      if constexpr (MODE == 0) {
#pragma unroll
        for (int r = 0; r < 4; ++r)
          of32[(size_t)(mbase + r) * N + ncol] = acc[fm][fn][r];
      } else {
        const int hh = ncol >> 7;
        const int d  = ncol & 127;
        const bool rope = ((wc & 1) == 0) && (fn == 0);   // d<16, wave-uniform
#pragma unroll
        for (int r = 0; r < 4; ++r) {
          float val = acc[fm][fn][r];
          const int m  = mbase + r;
          const int t  = m & (T_SEQ - 1);
          const int bb = m >> 11;
          if (rope) {
            float partner = __shfl_xor(val, 8);           // partner d^8
            float invf = exp2f(-(float)(d & 7) * 1.6609640474436813f);
            float ang = (float)t * invf;
            float sn, cn;
            sincosf(ang, &sn, &cn);
            float rot = (d < 8) ? -partner : partner;
            val = val * cn + rot * sn;
          }
          val *= gain[hh] * 0.12751742676f;               // fold 1/sqrt(128)*log2e
          obf[(size_t)((bb * NH + hh) * T_SEQ + t) * HD + d] = f2bf(val);
        }
      }
    }
  }
}

// ---------------- fused K+V projection (128-tile) ----------------
// W = [k_w; v_w], N=1024. Block n-tile = exactly one head (block-uniform hh).
// hh<4: K head — RoPE(d<16), bf16 (B,NKV,T,HD).
// hh>=4: V head — V^T written DIRECTLY (via padded LDS re-tile) to Vt (B,NKV,HD,T);
//        fp32 second output = kv-head 0 broadcast to all NKV slots.
__launch_bounds__(256, 2)
__global__ void gemm_kv(const unsigned short* __restrict__ A,
                        const unsigned short* __restrict__ W,
                        unsigned short* __restrict__ Kout,
                        unsigned short* __restrict__ Vt,
                        float* __restrict__ vout)
{
  __shared__ alignas(16) short As[128 * 64];
  __shared__ alignas(16) short Bs[128 * 64];
  __shared__ alignas(16) short Ts[128 * 132];   // [d][t] pad-132 transpose tile
  const int K = CDIM;
  const int tid = threadIdx.x;
  const int lane = tid & 63, w = tid >> 6;
  const int wr = w >> 1, wc = w & 1;
  const int lr = lane & 15, lg = lane >> 4;

  const int nwg  = gridDim.x * gridDim.y;       // 512, %8==0
  const int orig = blockIdx.y * gridDim.x + blockIdx.x;
  const int cpx  = nwg >> 3;
  const int swz  = (orig & 7) * cpx + (orig >> 3);
  const int m0 = (swz / gridDim.x) * 128, n0 = (swz % gridDim.x) * 128;

  f32x4 acc[4][4] = {};

  const int nkt = K >> 6;
  for (int kt = 0; kt < nkt; ++kt) {
    __syncthreads();
#pragma unroll
    for (int q = 0; q < 4; ++q) {
      int s = (w * 4 + q) * 64 + lane;
      int row = s >> 3;
      int cs2 = (s & 7) ^ (row & 7);
      gload_lds16(A + (size_t)(m0 + row) * K + (kt << 6) + cs2 * 8,
                  (char*)As + (w * 4 + q) * 1024);
      gload_lds16(W + (size_t)(n0 + row) * K + (kt << 6) + cs2 * 8,
                  (char*)Bs + (w * 4 + q) * 1024);
    }
    __syncthreads();
#pragma unroll
    for (int ks = 0; ks < 2; ++ks) {
      short8 af[4], bfr[4];
#pragma unroll
      for (int i = 0; i < 4; ++i) {
        int ra = wr * 64 + i * 16 + lr;
        int rb = wc * 64 + i * 16 + lr;
        af[i]  = *(const short8*)(As + ra * 64 + (((ks * 4 + lg) ^ (ra & 7)) << 3));
        bfr[i] = *(const short8*)(Bs + rb * 64 + (((ks * 4 + lg) ^ (rb & 7)) << 3));
      }
#pragma unroll
      for (int i = 0; i < 4; ++i)
#pragma unroll
        for (int j = 0; j < 4; ++j)
          acc[i][j] = mfma_bf16(af[i], bfr[j], acc[i][j]);
    }
  }

  const int hh = n0 >> 7;           // block-uniform head index
  const int bb = m0 >> 11;          // block-uniform batch
  const int tb = m0 & (T_SEQ - 1);  // block-uniform t base

  if (hh < 4) {
    // ---- K head: RoPE on d<16, linear bf16 write ----
#pragma unroll
    for (int i = 0; i < 4; ++i) {
      const int tl = wr * 64 + i * 16 + lg * 4;
#pragma unroll
      for (int j = 0; j < 4; ++j) {
        const int d = wc * 64 + j * 16 + lr;
        const bool rope = (wc == 0) && (j == 0);   // d<16, wave-uniform
#pragma unroll
        for (int r = 0; r < 4; ++r) {
          float val = acc[i][j][r];
          const int t = tb + tl + r;
          if (rope) {
            float partner = __shfl_xor(val, 8);
            float invf = exp2f(-(float)(d & 7) * 1.6609640474436813f);
            float ang = (float)t * invf;
            float sn, cn;
            sincosf(ang, &sn, &cn);
            float rot = (d < 8) ? -partner : partner;
            val = val * cn + rot * sn;
          }
          Kout[(size_t)((bb * NKV + hh) * T_SEQ + t) * HD + d] = f2bf(val);
        }
      }
    }
  } else {
    // ---- V head: vout broadcast (head 0) + transpose via LDS -> Vt ----
    const int hv = hh - 4;
#pragma unroll
    for (int i = 0; i < 4; ++i) {
      const int tl = wr * 64 + i * 16 + lg * 4;
#pragma unroll
      for (int j = 0; j < 4; ++j) {
        const int d = wc * 64 + j * 16 + lr;
        if (hv == 0) {
#pragma unroll
          for (int r = 0; r < 4; ++r) {
            float val = acc[i][j][r];
#pragma unroll
            for (int rep = 0; rep < NKV; ++rep)
              vout[(size_t)((bb * NKV + rep) * T_SEQ + tb + tl + r) * HD + d] = val;
          }
        }
        uint2 w2;
        w2.x = pk_bf16(acc[i][j][0], acc[i][j][1]);
        w2.y = pk_bf16(acc[i][j][2], acc[i][j][3]);
        *(uint2*)(Ts + d * 132 + tl) = w2;
      }
    }
    __syncthreads();
    // coalesced V^T writeout: thread pair covers one d row (128 t)
    const int d = tid >> 1, off = (tid & 1) * 64;
    unsigned short* dst = Vt + ((size_t)(bb * NKV + hv) * HD + d) * T_SEQ + tb + off;
    const short* srcp = Ts + d * 132 + off;
#pragma unroll
    for (int jj = 0; jj < 8; ++jj)
      *(short8*)(dst + jj * 8) = *(const short8*)(srcp + jj * 8);
  }
}

// ---------------- flash attention, causal, GQA ----------------
// Dual-head (2 q-heads share 1 kv-head -> K/V LDS frags read once, reused) on
// a QBLK=64 / 4-wave / 256-thr block: LDS = 80 KB -> 2 blocks/CU, 512 blocks.
// KVBLK=64 (V^T rows = 128 B = exactly one cache line; KVBLK=32 regressed 3.7x
// via half-line fetches + halved per-barrier work — round-13 post-mortem).
// Fixed-baseline softmax P = 2^(S-16) in MFMA C-init. Counted-vmcnt K/V-split
// pipeline (ledger 4/8/4, never drains in-loop). All barriers hardened.
__launch_bounds__(256, 2)
__global__ void attn_fwd(const unsigned short* __restrict__ Q,
                         const unsigned short* __restrict__ Kg,
                         const unsigned short* __restrict__ Vt,
                         unsigned short* __restrict__ O)
{
  __shared__ alignas(16) short Ks[2][64 * 128];   // 32 KB
  __shared__ alignas(16) short Vs[2][128 * 64];   // 32 KB
  __shared__ alignas(16) short Ps[128 * 64];      // 16 KB (head0 rows 0-63, head1 +64)

  const int pairi = blockIdx.x;                   // 0..15 qtile pair
  const int hp = blockIdx.y, b = blockIdx.z;      // head pair 0..7
  const int kvh = hp >> 1;
  const int h0 = kvh * 4 + (hp & 1) * 2, h1 = h0 + 1;
  const int tid = threadIdx.x, lane = tid & 63, w = tid >> 6;   // w 0..3
  const int lr = lane & 15, lg = lane >> 4;

  const unsigned short* Qb0 = Q  + ((size_t)(b * NH  + h0)  * T_SEQ) * HD;
  const unsigned short* Qb1 = Q  + ((size_t)(b * NH  + h1)  * T_SEQ) * HD;
  const unsigned short* Kb  = Kg + ((size_t)(b * NKV + kvh) * T_SEQ) * HD;
  const unsigned short* Vtb = Vt + ((size_t)(b * NKV + kvh) * HD) * T_SEQ;

  auto stageK = [&](int kt, int buf) {
#pragma unroll
    for (int i = 0; i < 4; ++i) {   // 64 rows x 16 chunks = 1024, 4 per thread
      int s = i * 256 + tid;
      int row = s >> 4, c = s & 15, cs = c ^ (row & 7);
      gload_lds16(Kb + (size_t)(kt * 64 + row) * HD + cs * 8,
                  (char*)&Ks[buf][0] + i * 4096 + w * 1024);
    }
  };
  auto stageV = [&](int kt, int buf) {
#pragma unroll
    for (int i = 0; i < 4; ++i) {   // 128 rows x 8 chunks = 1024
      int s = i * 256 + tid;
      int row = s >> 3, c = s & 7, cs = c ^ (row & 7);
      gload_lds16(Vtb + (size_t)row * T_SEQ + kt * 64 + cs * 8,
                  (char*)&Vs[buf][0] + i * 4096 + w * 1024);
    }
  };

  auto run_seg = [&](int qtile) {
    const int q0 = qtile * 64;
    const int rw = q0 + w * 16;       // wave's first q row
    const int qg = rw + lr;           // lane's q row (same for both heads)

    short8 qf0[4], qf1[4];
#pragma unroll
    for (int ks = 0; ks < 4; ++ks) {
      qf0[ks] = *(const short8*)(Qb0 + (size_t)qg * HD + ks * 32 + lg * 8);
      qf1[ks] = *(const short8*)(Qb1 + (size_t)qg * HD + ks * 32 + lg * 8);
    }

    f32x4 acc0[8] = {}, acc1[8] = {};
    float lrow0 = 0.0f, lrow1 = 0.0f;

    const int nkt = qtile + 1;        // KVBLK=64; all waves active every tile

    stageK(0, 0);
    stageV(0, 0);
    asm volatile("s_waitcnt vmcnt(4)" ::: "memory");   // K(0) landed, V(0) in flight
    barrier_hard();
    int cur = 0;

    const f32x4 minit = {-16.f, -16.f, -16.f, -16.f};  // fixed softmax baseline

    for (int kt = 0; kt < nkt; ++kt) {
      const int tn = (kt + 1 < nkt) ? kt + 1 : kt;
      stageK(tn, cur ^ 1);            // out: V(t)4 + K(t+1)4 = 8

      {
        const short* KL = &Ks[cur][0];
        f32x4 s0[4] = {minit, minit, minit, minit};
        f32x4 s1[4] = {minit, minit, minit, minit};
        __builtin_amdgcn_s_setprio(1);
#pragma unroll
        for (int kb = 0; kb < 4; ++kb) {
          int key = kb * 16 + lr;
#pragma unroll
          for (int ks = 0; ks < 4; ++ks) {
            short8 kf = *(const short8*)(KL + key * 128 + (((ks * 4 + lg) ^ (key & 7)) << 3));
            s0[kb] = mfma_bf16(kf, qf0[ks], s0[kb]);
            s1[kb] = mfma_bf16(kf, qf1[ks], s1[kb]);
          }
        }
        __builtin_amdgcn_s_setprio(0);

        if (kt == qtile) {            // diagonal tile: identical mask both heads
#pragma unroll
          for (int kb = 0; kb < 4; ++kb)
#pragma unroll
            for (int r = 0; r < 4; ++r)
              if (kt * 64 + kb * 16 + lg * 4 + r > qg) {
                s0[kb][r] = -3.0e38f;
                s1[kb][r] = -3.0e38f;
              }
        }

        // P = 2^(S-16); in-lane sums; pack to LDS (b64 writes)
        float sum0 = 0.f, sum1 = 0.f;
#pragma unroll
        for (int kb = 0; kb < 4; ++kb) {
          int cc = (kb * 2 + (lg >> 1)) ^ (lr & 7);
          {
            float p0 = exp2_fast(s0[kb][0]);
            float p1 = exp2_fast(s0[kb][1]);
            float p2 = exp2_fast(s0[kb][2]);
            float p3 = exp2_fast(s0[kb][3]);
            sum0 += (p0 + p1) + (p2 + p3);
            uint2 w2;
            w2.x = pk_bf16(p0, p1);
            w2.y = pk_bf16(p2, p3);
            *(uint2*)(Ps + (w * 16 + lr) * 64 + (cc << 3) + ((lg & 1) << 2)) = w2;
          }
          {
            float p0 = exp2_fast(s1[kb][0]);
            float p1 = exp2_fast(s1[kb][1]);
            float p2 = exp2_fast(s1[kb][2]);
            float p3 = exp2_fast(s1[kb][3]);
            sum1 += (p0 + p1) + (p2 + p3);
            uint2 w2;
            w2.x = pk_bf16(p0, p1);
            w2.y = pk_bf16(p2, p3);
            *(uint2*)(Ps + (64 + w * 16 + lr) * 64 + (cc << 3) + ((lg & 1) << 2)) = w2;
          }
        }
        lrow0 += sum0;
        lrow1 += sum1;
      }

      stageV(tn, cur ^ 1);            // out: 12
      asm volatile("s_waitcnt vmcnt(8)" ::: "memory");  // V(t) landed
      barrier_hard();

      {
        const short* VL = &Vs[cur][0];
        const int r0 = w * 16 + lr, r1 = 64 + w * 16 + lr;
        short8 pf00 = *(const short8*)(Ps + r0 * 64 + (((0 + lg) ^ (lr & 7)) << 3));
        short8 pf01 = *(const short8*)(Ps + r0 * 64 + (((4 + lg) ^ (lr & 7)) << 3));
        short8 pf10 = *(const short8*)(Ps + r1 * 64 + (((0 + lg) ^ (lr & 7)) << 3));
        short8 pf11 = *(const short8*)(Ps + r1 * 64 + (((4 + lg) ^ (lr & 7)) << 3));
        __builtin_amdgcn_s_setprio(1);
#pragma unroll
        for (int db = 0; db < 8; ++db) {
          int vrow = db * 16 + lr;
          short8 v0 = *(const short8*)(VL + vrow * 64 + (((0 + lg) ^ (vrow & 7)) << 3));
          short8 v1 = *(const short8*)(VL + vrow * 64 + (((4 + lg) ^ (vrow & 7)) << 3));
          acc0[db] = mfma_bf16(v0, pf00, acc0[db]);
          acc0[db] = mfma_bf16(v1, pf01, acc0[db]);
          acc1[db] = mfma_bf16(v0, pf10, acc1[db]);
          acc1[db] = mfma_bf16(v1, pf11, acc1[db]);
        }
        __builtin_amdgcn_s_setprio(0);
      }

      asm volatile("s_waitcnt vmcnt(4)" ::: "memory");  // K(t+1) landed
      barrier_hard();
      cur ^= 1;
    }

    asm volatile("s_waitcnt vmcnt(0)" ::: "memory");
    barrier_hard();

    // epilogue: cross-lane lrow reduce once per segment, normalize + store both heads
    lrow0 += __shfl_xor(lrow0, 16); lrow0 += __shfl_xor(lrow0, 32);
    lrow1 += __shfl_xor(lrow1, 16); lrow1 += __shfl_xor(lrow1, 32);
    float inv0 = 1.0f / lrow0, inv1 = 1.0f / lrow1;
#pragma unroll
    for (int db = 0; db < 8; ++db) {
      uint2 o2;
      o2.x = pk_bf16(acc0[db][0] * inv0, acc0[db][1] * inv0);
      o2.y = pk_bf16(acc0[db][2] * inv0, acc0[db][3] * inv0);
      *(uint2*)(O + (size_t)(b * T_SEQ + qg) * CDIM + h0 * HD + db * 16 + lg * 4) = o2;
      uint2 o3;
      o3.x = pk_bf16(acc1[db][0] * inv1, acc1[db][1] * inv1);
      o3.y = pk_bf16(acc1[db][2] * inv1, acc1[db][3] * inv1);
      *(uint2*)(O + (size_t)(b * T_SEQ + qg) * CDIM + h1 * HD + db * 16 + lg * 4) = o3;
    }
  };

  run_seg(31 - pairi);   // heavy member of the pair
  run_seg(pairi);        // light member -> uniform 33 tiles total per block
}

// ---------------- launch ----------------
extern "C" void kernel_launch(void* const* d_in, const int* in_sizes, int n_in,
                              void* d_out, int out_size, void* d_ws, size_t ws_size,
                              hipStream_t stream) {
  (void)in_sizes; (void)n_in; (void)out_size; (void)ws_size;
  const float* x    = (const float*)d_in[0];
  const float* qw   = (const float*)d_in[1];
  const float* kw   = (const float*)d_in[2];
  const float* vw   = (const float*)d_in[3];
  const float* ow   = (const float*)d_in[4];
  const float* gain = (const float*)d_in[5];
  float* out  = (float*)d_out;
  float* vout = out + (size_t)NB * T_SEQ * CDIM;

  char* ws = (char*)d_ws;
  unsigned short* xb  = (unsigned short*)(ws);              // 33554432 B (also Ab)
  unsigned short* Qb  = (unsigned short*)(ws + 33554432);   // 33554432
  unsigned short* Kb  = (unsigned short*)(ws + 67108864);   //  8388608
  unsigned short* qwb = (unsigned short*)(ws + 83886080);   //  8388608 (later: Vt)
  unsigned short* kwb = (unsigned short*)(ws + 92274688);   //  2097152 (+vwb contiguous)
  unsigned short* vwb = (unsigned short*)(ws + 94371840);   //  2097152
  unsigned short* owb = (unsigned short*)(ws + 96468992);   //  8388608  -> 104857600 total
  unsigned short* Ab  = xb;
  unsigned short* Vtb = qwb;   // [B*NKV][HD][T] bf16; qwb dead after gemm256<1>

  cvt_all<<<3328, 256, 0, stream>>>(x, qw, kw, vw, ow, xb, qwb, kwb, vwb, owb);

  gemm256<1><<<dim3(8, 32), 512, 0, stream>>>(xb, qwb, CDIM, CDIM, Qb, nullptr, gain);
  gemm_kv<<<dim3(8, 64), 256, 0, stream>>>(xb, kwb, Kb, Vtb, vout);

  attn_fwd<<<dim3(16, 8, 4), 256, 0, stream>>>(Qb, Kb, Vtb, Ab);

  gemm256<0><<<dim3(8, 32), 512, 0, stream>>>(Ab, owb, CDIM, CDIM, nullptr, out, nullptr);
}